// Round 12
// baseline (318.077 us; speedup 1.0000x reference)
//
#include <hip/hip_runtime.h>

#define SEQ_T   2048
#define BATCH_N 4096
#define LOG2E   1.4426950408889634f
#define K_SEG   16
#define NSEG    (SEQ_T / K_SEG)   // 128 segments

// DPP mov: quad_perm = 0x00..0xFF, ROW_MIRROR = 0x140, ROW_HALF_MIRROR = 0x141
#define DPPF(v, ctrl) __int_as_float(__builtin_amdgcn_mov_dpp(__float_as_int(v), (ctrl), 0xF, 0xF, true))
#define RHM 0x141   // quad u -> u^1 (h is quad-uniform; intra-quad scramble ok)
#define MIR 0x140   // quad u -> u^3

// Layer-split wave specialization (R8 skeleton) + work migration:
//   wave 0 = "A": layer 0 for 4 chains (16 lanes/chain, UNIT-MAJOR 4u+r).
//                 After each cell, A ALSO computes B's input projection
//                 px1[row] = Wih1[row]. h0 + b1 (4 fmas, reuses h0 mirrors)
//                 and writes it to the ring (all 64 lanes, 2-way bank-free).
//   wave 1 = "B": layer 1, same chains, one 16-step segment behind. Batch-
//                 reads its 16 px1 scalars at segment start (latency hidden),
//                 cell starts directly at the recurrent dot.
// Purpose: A(~37 instr) vs B(~28 instr) phase-drift decorrelates the two
// waves' trans-latency stalls (R8 had them phase-locked); B's chain shortens.
// ring[32][4][16] = 8 KB. Barrier every 16 steps; parity halves disjoint.
// 1024 blocks x 2 waves = 2048 waves = 2 waves/SIMD.
__global__ __launch_bounds__(128, 2) void lstm2_split(
    const float* __restrict__ x,
    const float* __restrict__ Wih0, const float* __restrict__ Whh0,
    const float* __restrict__ bih0, const float* __restrict__ bhh0,
    const float* __restrict__ Wih1, const float* __restrict__ Whh1,
    const float* __restrict__ bih1, const float* __restrict__ bhh1,
    float* __restrict__ out)
{
    __shared__ float ring[32][4][16];   // [slot][chain-in-block][gate-row]=px1

    const int wv    = threadIdx.x >> 6;     // 0 = A (layer0), 1 = B (layer1)
    const int lane  = threadIdx.x & 63;
    const int cpos  = lane >> 4;            // chain-in-block 0..3
    const int g16   = lane & 15;
    const int u     = g16 >> 2;             // hidden unit (quad)
    const int r     = g16 & 3;              // role 0=i 1=f 2=g 3=o
    const int row   = r * 4 + u;            // PyTorch gate-row
    const int chain = blockIdx.x * 4 + cpos;
    const bool isA  = (wv == 0);

    // Fold -log2e (sigmoid) / -2log2e (tanh row) into weights & bias.
    const float srow = (r == 2) ? (-2.0f * LOG2E) : (-LOG2E);
    // g-row activation folds the cell-tanh arg scale: cs tracks -2log2e * c.
    const float csc = -2.0f * LOG2E;
    const float ka = (r == 2) ? 2.0f * csc : 1.0f;
    const float kb = (r == 2) ? -csc       : 0.0f;

    float whh[4];                       // my layer's recurrent row (u-relative)
    float h = 0.f, ha = 0.f, hb2 = 0.f, hc = 0.f, cs = 0.f;

    // one cell step from pre-activation base acc -> updates cs, h, mirrors
    auto cell = [&](float acc) {
        acc = fmaf(whh[0], h, fmaf(whh[1], ha,
              fmaf(whh[2], hb2, fmaf(whh[3], hc, acc))));
        float e = __builtin_amdgcn_exp2f(acc);
        float s = __builtin_amdgcn_rcpf(1.0f + e);
        float a = fmaf(ka, s, kb);
        float iv = DPPF(a, 0x00), fv = DPPF(a, 0x55);
        float gv = DPPF(a, 0xAA), ov = DPPF(a, 0xFF);
        cs = fmaf(fv, cs, iv * gv);
        float z  = __builtin_amdgcn_exp2f(cs);
        float t2 = fmaf(2.0f, __builtin_amdgcn_rcpf(1.0f + z), -1.0f);
        h  = ov * t2;
        ha = DPPF(h, RHM);
        hc = DPPF(h, MIR);
        hb2 = DPPF(ha, MIR);
    };

    const char* __restrict__ xb = (const char*)x;
    char* __restrict__ ob = (char*)out;

    if (isA) {
        // ---------------- layer-0 wave ----------------
        float win[4], wpx[4];
#pragma unroll
        for (int d = 0; d < 4; ++d) {
            win[d] = Wih0[row * 4 + d]       * srow;  // x dot: natural order
            whh[d] = Whh0[row * 4 + (u ^ d)] * srow;  // recurrent: u-relative
            wpx[d] = Wih1[row * 4 + (u ^ d)] * srow;  // px1 dot: u-relative
        }
        const float bb  = (bih0[row] + bhh0[row]) * srow;
        const float bpx = (bih1[row] + bhh1[row]) * srow;

        const unsigned xhome = (unsigned)chain * 16u;
        const unsigned XCL   = xhome + 2047u * 65536u;
        float4 xbuf[8];
        unsigned xoff = xhome;
#pragma unroll
        for (int i = 0; i < 8; ++i) {           // prologue: x(0..7) in flight
            xbuf[i] = *(const float4*)(xb + xoff);
            xoff += 65536u;
        }
        for (int seg = 0; seg <= NSEG; ++seg) {
            __syncthreads();
            if (seg < NSEG) {
                const int sb = (seg & 1) * K_SEG;
                if (seg < NSEG - 1) {
                    // unclamped main path (refill target always < SEQ_T)
#pragma unroll
                    for (int i = 0; i < K_SEG; ++i) {
                        const float4 xv = xbuf[i & 7];
                        xbuf[i & 7] = *(const float4*)(xb + xoff);
                        xoff += 65536u;
                        float acc = fmaf(win[0], xv.x, fmaf(win[1], xv.y,
                                    fmaf(win[2], xv.z, fmaf(win[3], xv.w, bb))));
                        cell(acc);
                        float px = fmaf(wpx[0], h, fmaf(wpx[1], ha,
                                   fmaf(wpx[2], hb2, fmaf(wpx[3], hc, bpx))));
                        ring[sb + i][cpos][row] = px;
                    }
                } else {
                    // final segment: clamp refills at the sequence end
#pragma unroll
                    for (int i = 0; i < K_SEG; ++i) {
                        const float4 xv = xbuf[i & 7];
                        unsigned off = (xoff < XCL) ? xoff : XCL;
                        xbuf[i & 7] = *(const float4*)(xb + off);
                        xoff += 65536u;
                        float acc = fmaf(win[0], xv.x, fmaf(win[1], xv.y,
                                    fmaf(win[2], xv.z, fmaf(win[3], xv.w, bb))));
                        cell(acc);
                        float px = fmaf(wpx[0], h, fmaf(wpx[1], ha,
                                   fmaf(wpx[2], hb2, fmaf(wpx[3], hc, bpx))));
                        ring[sb + i][cpos][row] = px;
                    }
                }
            }
        }
    } else {
        // ---------------- layer-1 wave ----------------
#pragma unroll
        for (int d = 0; d < 4; ++d)
            whh[d] = Whh1[row * 4 + (u ^ d)] * srow;

        unsigned ooff = (unsigned)(chain * 16 + u * 4);   // out[0][chain][u]
        for (int seg = 0; seg <= NSEG; ++seg) {
            __syncthreads();
            if (seg > 0) {
                const int sb = ((seg - 1) & 1) * K_SEG;
                float pxr[K_SEG];
                // batch-read all 16 px1 scalars (latency hidden by batching)
#pragma unroll
                for (int i = 0; i < K_SEG; ++i)
                    pxr[i] = ring[sb + i][cpos][row];
#pragma unroll
                for (int i = 0; i < K_SEG; ++i) {
                    cell(pxr[i]);
                    if (r == 0) *(float*)(ob + ooff) = h;   // h1 of my unit
                    ooff += 65536u;
                }
            }
        }
    }
}

extern "C" void kernel_launch(void* const* d_in, const int* in_sizes, int n_in,
                              void* d_out, int out_size, void* d_ws, size_t ws_size,
                              hipStream_t stream) {
    const float* x    = (const float*)d_in[0];
    const float* Wih0 = (const float*)d_in[1];
    const float* Whh0 = (const float*)d_in[2];
    const float* bih0 = (const float*)d_in[3];
    const float* bhh0 = (const float*)d_in[4];
    const float* Wih1 = (const float*)d_in[5];
    const float* Whh1 = (const float*)d_in[6];
    const float* bih1 = (const float*)d_in[7];
    const float* bhh1 = (const float*)d_in[8];
    float* out = (float*)d_out;

    // 1024 blocks x 2 waves (1 A + 1 B) = 2048 waves = 2 waves/SIMD
    dim3 grid(1024), block(128);
    hipLaunchKernelGGL(lstm2_split, grid, block, 0, stream,
                       x, Wih0, Whh0, bih0, bhh0, Wih1, Whh1, bih1, bhh1, out);
}

// Round 14
// 231.074 us; speedup vs baseline: 1.3765x; 1.3765x over previous
//
#include <hip/hip_runtime.h>

#define SEQ_T   2048
#define BATCH_N 4096
#define LOG2E   1.4426950408889634f
#define K_SEG   16
#define NSEG    (SEQ_T / K_SEG)   // 128 segments

// One LSTM cell step, hand-scheduled, DPP-fused operands (VOP2 src0-DPP).
// 16-lane chain group, UNIT-MAJOR lane = 4u + r; h, cs are quad-uniform.
// Recurrent dot taps h's quad-mirrors directly (w_d pairs with h_{u^d}):
//   w0: plain, w1: row_half_mirror (u^1), w2: row_ror:8 (u^2), w3: row_mirror (u^3)
// Gate gather fused into consumers via quad_perm (only g needs a real mov).
//
// COMPLETE gfx9 manual-wait-state audit (compiler does this for its own code,
// asm must self-insert):
//  (a) trans op (v_exp/v_rcp) write -> ANY consumer: 1 wait  => s_nop 0 after
//      every v_exp/v_rcp whose result is read next.
//  (b) VALU write -> DPP read of that VGPR: 2 waits => s_nop 1 before the
//      quad_perm reads of `a`; s_nop 3 at entry covers the seam (h written by
//      the previous cell's final v_mul).
//  (c) SALU EXEC write -> DPP: 5 waits => entry gap = >=1 caller instr +
//      1 fmac + 4 nop cycles >= 5 since any saveexec/restore in the caller.
//  Plain (non-DPP) VALU->VALU reads are HW-interlocked.
__device__ __forceinline__ void cell_asm(float& acc, float& h, float& cs,
                                         float w0, float w1, float w2, float w3,
                                         float ka, float kb) {
    float t, a, gv, cn, hn;
    asm("v_fmac_f32 %[acc], %[h], %[w0]\n\t"            // plain h (interlocked)
        "s_nop 3\n\t"                                   // (b)/(c) for DPP h reads
        "v_fmac_f32 %[acc], %[h], %[w1] row_half_mirror row_mask:0xf bank_mask:0xf\n\t"
        "v_fmac_f32 %[acc], %[h], %[w2] row_ror:8 row_mask:0xf bank_mask:0xf\n\t"
        "v_fmac_f32 %[acc], %[h], %[w3] row_mirror row_mask:0xf bank_mask:0xf\n\t"
        "v_exp_f32 %[t], %[acc]\n\t"
        "s_nop 0\n\t"                                   // (a)
        "v_add_f32 %[t], 1.0, %[t]\n\t"
        "v_rcp_f32 %[t], %[t]\n\t"
        "s_nop 0\n\t"                                   // (a)
        "v_fma_f32 %[a], %[ka], %[t], %[kb]\n\t"
        "s_nop 1\n\t"                                   // (b) a -> quad_perm
        "v_mov_b32 %[gv], %[a] quad_perm:[2,2,2,2] row_mask:0xf bank_mask:0xf\n\t"
        "v_mul_f32 %[cn], %[a], %[gv] quad_perm:[0,0,0,0] row_mask:0xf bank_mask:0xf\n\t"
        "v_fmac_f32 %[cn], %[a], %[cs] quad_perm:[1,1,1,1] row_mask:0xf bank_mask:0xf\n\t"
        "v_exp_f32 %[t], %[cn]\n\t"
        "s_nop 0\n\t"                                   // (a)
        "v_add_f32 %[t], 1.0, %[t]\n\t"
        "v_rcp_f32 %[t], %[t]\n\t"
        "s_nop 0\n\t"                                   // (a)
        "v_fma_f32 %[hn], 2.0, %[t], -1.0\n\t"
        "v_mul_f32 %[h], %[a], %[hn] quad_perm:[3,3,3,3] row_mask:0xf bank_mask:0xf\n\t"
        : [acc] "+v"(acc), [h] "+v"(h),
          [t] "=&v"(t), [a] "=&v"(a), [gv] "=&v"(gv),
          [cn] "=&v"(cn), [hn] "=&v"(hn)
        : [cs] "v"(cs), [w0] "v"(w0), [w1] "v"(w1), [w2] "v"(w2), [w3] "v"(w3),
          [ka] "v"(ka), [kb] "v"(kb));
    cs = cn;   // register rename, no mov emitted
}

// Layer-split wave specialization (R8 skeleton, unchanged structure):
//   wave 0 = "A": layer 0 for 4 chains (16 lanes/chain, UNIT-MAJOR 4u+r)
//   wave 1 = "B": layer 1, same chains, one 16-step segment behind
// Handoff ring[32 slots][4 chains][4 units] (2 KB). A writes h0 (r==0 lanes);
// B reads ds_read_b128 -> all 4 h0 components IN-LANE. Barrier every 16
// steps; segment parity gives disjoint ring halves.
// 1024 blocks x 2 waves = 2048 waves = 2 waves/SIMD.
__global__ __launch_bounds__(128, 2) void lstm2_split(
    const float* __restrict__ x,
    const float* __restrict__ Wih0, const float* __restrict__ Whh0,
    const float* __restrict__ bih0, const float* __restrict__ bhh0,
    const float* __restrict__ Wih1, const float* __restrict__ Whh1,
    const float* __restrict__ bih1, const float* __restrict__ bhh1,
    float* __restrict__ out)
{
    __shared__ float ring[32][4][4];   // [slot][chain-in-block][unit]

    const int wv    = threadIdx.x >> 6;     // 0 = A (layer0), 1 = B (layer1)
    const int lane  = threadIdx.x & 63;
    const int cpos  = lane >> 4;            // chain-in-block 0..3
    const int g16   = lane & 15;
    const int u     = g16 >> 2;             // hidden unit (quad)
    const int r     = g16 & 3;              // role 0=i 1=f 2=g 3=o
    const int row   = r * 4 + u;            // PyTorch gate-row
    const int chain = blockIdx.x * 4 + cpos;
    const bool isA  = (wv == 0);

    // Fold -log2e (sigmoid) / -2log2e (tanh row) into weights & bias.
    // Input dots natural order (x / LDS-h0 in-lane); recurrent dots
    // u-relative order matching the asm DPP sequence:
    //   w0 <-> u, w1 <-> u^1 (RHM), w2 <-> u^2 (ROR8), w3 <-> u^3 (MIR).
    const float srow = (r == 2) ? (-2.0f * LOG2E) : (-LOG2E);
    float win[4], whh[4], bb;
    if (isA) {
#pragma unroll
        for (int d = 0; d < 4; ++d) {
            win[d] = Wih0[row * 4 + d]       * srow;
            whh[d] = Whh0[row * 4 + (u ^ d)] * srow;
        }
        bb = (bih0[row] + bhh0[row]) * srow;
    } else {
#pragma unroll
        for (int d = 0; d < 4; ++d) {
            win[d] = Wih1[row * 4 + d]       * srow;
            whh[d] = Whh1[row * 4 + (u ^ d)] * srow;
        }
        bb = (bih1[row] + bhh1[row]) * srow;
    }
    // g-row activation folds the cell-tanh arg scale: cs tracks -2log2e * c.
    const float csc = -2.0f * LOG2E;
    const float ka = (r == 2) ? 2.0f * csc : 1.0f;
    const float kb = (r == 2) ? -csc       : 0.0f;

    const char* __restrict__ xb = (const char*)x;
    char* __restrict__ ob = (char*)out;

    float h = 0.f, cs = 0.f;

    if (isA) {
        // ---------------- layer-0 wave ----------------
        const unsigned xhome = (unsigned)chain * 16u;
        const unsigned XCL   = xhome + 2047u * 65536u;
        float4 xbuf[8];
        unsigned xoff = xhome;
#pragma unroll
        for (int i = 0; i < 8; ++i) {           // prologue: x(0..7) in flight
            xbuf[i] = *(const float4*)(xb + xoff);
            xoff += 65536u;
        }
        for (int seg = 0; seg <= NSEG; ++seg) {
            __syncthreads();
            if (seg < NSEG) {
                float (*slot)[4] = ring[(seg & 1) * K_SEG];
#pragma unroll
                for (int i = 0; i < K_SEG; ++i) {
                    const float4 xv = xbuf[i & 7];
                    unsigned off = (xoff < XCL) ? xoff : XCL;   // clamp tail
                    xbuf[i & 7] = *(const float4*)(xb + off);
                    xoff += 65536u;
                    float acc = fmaf(win[0], xv.x, fmaf(win[1], xv.y,
                                fmaf(win[2], xv.z, fmaf(win[3], xv.w, bb))));
                    cell_asm(acc, h, cs, whh[0], whh[1], whh[2], whh[3], ka, kb);
                    if (r == 0) slot[i * 4 + cpos][u] = h;
                }
            }
        }
    } else {
        // ---------------- layer-1 wave ----------------
        unsigned ooff = (unsigned)(chain * 16 + u * 4);   // out[0][chain][u]
        for (int seg = 0; seg <= NSEG; ++seg) {
            __syncthreads();
            if (seg > 0) {
                const float (*slot)[4] = ring[((seg - 1) & 1) * K_SEG];
                float4 hr[8];
#pragma unroll
                for (int hf = 0; hf < 2; ++hf) {
#pragma unroll
                    for (int s = 0; s < 8; ++s)
                        hr[s] = *(const float4*)&slot[(hf * 8 + s) * 4 + cpos][0];
#pragma unroll
                    for (int i = 0; i < 8; ++i) {
                        const float4 X = hr[i];
                        float acc = fmaf(win[0], X.x, fmaf(win[1], X.y,
                                    fmaf(win[2], X.z, fmaf(win[3], X.w, bb))));
                        cell_asm(acc, h, cs, whh[0], whh[1], whh[2], whh[3], ka, kb);
                        if (r == 0) *(float*)(ob + ooff) = h;
                        ooff += 65536u;
                    }
                }
            }
        }
    }
}

extern "C" void kernel_launch(void* const* d_in, const int* in_sizes, int n_in,
                              void* d_out, int out_size, void* d_ws, size_t ws_size,
                              hipStream_t stream) {
    const float* x    = (const float*)d_in[0];
    const float* Wih0 = (const float*)d_in[1];
    const float* Whh0 = (const float*)d_in[2];
    const float* bih0 = (const float*)d_in[3];
    const float* bhh0 = (const float*)d_in[4];
    const float* Wih1 = (const float*)d_in[5];
    const float* Whh1 = (const float*)d_in[6];
    const float* bih1 = (const float*)d_in[7];
    const float* bhh1 = (const float*)d_in[8];
    float* out = (float*)d_out;

    // 1024 blocks x 2 waves (1 A + 1 B) = 2048 waves = 2 waves/SIMD
    dim3 grid(1024), block(128);
    hipLaunchKernelGGL(lstm2_split, grid, block, 0, stream,
                       x, Wih0, Whh0, bih0, bhh0, Wih1, Whh1, bih1, bhh1, out);
}